// Round 11
// baseline (119.476 us; speedup 1.0000x reference)
//
#include <hip/hip_runtime.h>
#include <cstdint>

// ChessGNN forward, MI355X.
// R9 = R8 numerics + 2 graphs per block (grid 1024): barriers per graph
//     halved, phases 4/5 fully thread-occupied, weights staged once per pair.
//     LDS 63,232B -> 2 blocks/CU. Live-across-barrier state kept at 16 f32.

#define BB   2048
#define NN   90
#define NP   96
#define CC   64
#define NH   4
#define HD   16
#define TPB  512
#define GRID (BB / 2)
#define DOUT 128
#define SXP  72      // sx / sh16 row pitch (f16)
#define SWP  72      // sWt row pitch (f16)
#define PPITCH 20    // sPh row pitch (f16)
#define NSLOT 19

typedef _Float16 f16;
typedef _Float16 f16x4 __attribute__((ext_vector_type(4)));
typedef _Float16 f16x8 __attribute__((ext_vector_type(8)));
typedef float f32x4 __attribute__((ext_vector_type(4)));
union U16x4 { f16x4 v; f16 e[4]; };
union U16x8 { f16x8 v; f16 e[8]; };

// LDS map (bytes), total 63,232:
//  [0,13824)      sxA f16[96][72] -> shA (phase-3 overlay)
//  [13824,27648)  sxB f16[96][72] -> shB
//  [27648,56448)  reg2 (28,800):
//     staging: sWt f16[64][72] @27648 | sInW f32[16][64] @36864
//              | sInb f32[64] @40960 | sXrA f32[90][17] @41216 | sXrB @47336
//     ph5-6:   sPh f16[2][360][20] @27648
//     ph7:     sRa f32[2][8][64] @27648 | sRb @31744
//  [56448,59328)  sSrc f32[2][4][90]
//  [59328,62208)  sDst f32[2][4][90]
//  [62208,62464)  sAs f32[64]   [62464,62720) sAd f32[64]
//  [62720,63232)  sST f32[128]
#define LDS_BYTES 63232

template <int LAYER>
__global__ __launch_bounds__(TPB, 4) void k_gat(
    const float* __restrict__ bp,
    const float* __restrict__ inW,
    const float* __restrict__ inb,
    const f16*   __restrict__ prevPre,
    const float* __restrict__ stPrev,
    const float* __restrict__ Wl,
    const float* __restrict__ asrc,
    const float* __restrict__ adst,
    f16*   __restrict__ outPre,
    float* __restrict__ partial,
    float* __restrict__ partialSq)
{
    __shared__ __align__(16) unsigned char lds[LDS_BYTES];
    f16*   sxA  = (f16*)lds;                 // also shA after phase 3
    f16*   sxB  = (f16*)(lds + 13824);       // also shB
    f16*   sWt  = (f16*)(lds + 27648);
    float* sInW = (float*)(lds + 36864);
    float* sInb = (float*)(lds + 40960);
    float* sXrA = (float*)(lds + 41216);
    float* sXrB = (float*)(lds + 47336);
    f16*   sPh  = (f16*)(lds + 27648);       // [2][360][20]
    float* sRa  = (float*)(lds + 27648);     // [2][8][64]
    float* sRb  = (float*)(lds + 31744);
    float* sSrc = (float*)(lds + 56448);     // [2][4][90]
    float* sDst = (float*)(lds + 59328);
    float* sAs  = (float*)(lds + 62208);
    float* sAd  = (float*)(lds + 62464);
    float* sST  = (float*)(lds + 62720);

    const int b2 = blockIdx.x * 2, t = threadIdx.x;
    const int cq = t & 15, ng = t >> 4;
    const int c4 = cq << 2;
    const int jcnt = (ng < NN - 64) ? 3 : 2;
    const int lane = t & 63, wv = t >> 6;
    const int lr = lane & 15, lg = lane >> 4;

    // ---------------- phase 1: stage weights / inputs; zero-pad rows 90-95
    for (int i = t; i < CC * CC; i += TPB) {
        int k = i >> 6, c = i & 63;
        sWt[c * SWP + k] = (f16)Wl[i];
    }
    if (t < NH * HD) { sAs[t] = asrc[t]; sAd[t] = adst[t]; }
    if (t < 2 * (NP - NN) * (SXP / 4)) {       // 216 quads
        int u = t;
        int g = u / 108; u -= g * 108;
        int r = u / 18, q = u - r * 18;
        f16x4 z = {(f16)0, (f16)0, (f16)0, (f16)0};
        f16* sx = g ? sxB : sxA;
        *(f16x4*)&sx[(NN + r) * SXP + q * 4] = z;
    }
    if (LAYER == 0) {
        for (int i = t; i < 16 * CC; i += TPB) sInW[i] = inW[i];
        if (t < CC) sInb[t] = inb[t];
        for (int i = t; i < 2 * 14 * NN; i += TPB) {
            int g = i / 1260, r = i - g * 1260;
            int p = r / NN, n = r - p * NN;
            float v = bp[(size_t)(b2 + g) * 1260 + r];
            (g ? sXrB : sXrA)[n * 17 + p] = v;
        }
        if (t < 2 * NN) {
            int g = t / NN, n = t - g * NN;
            int y = n / 9, x = n - y * 9;
            float* X = g ? sXrB : sXrA;
            X[n * 17 + 14] = (float)x / 9.0f;
            X[n * 17 + 15] = (float)y / 10.0f;
        }
    } else {
        if (t < 2 * CC) sST[t] = stPrev[t];
    }
    __syncthreads();

    // ---------------- phase 2: x -> sx (f16), both graphs
    if (LAYER == 0) {
        #pragma unroll
        for (int g = 0; g < 2; g++) {
            const float* sXr = g ? sXrB : sXrA;
            f16* sx = g ? sxB : sxA;
            const int n0 = ng, n1 = ng + 32, n2 = (jcnt == 3) ? ng + 64 : ng;
            float acc[3][4] = {};
            #pragma unroll 4
            for (int k = 0; k < 16; k++) {
                float4 w = *(const float4*)&sInW[k * CC + c4];
                float x0 = sXr[n0 * 17 + k], x1 = sXr[n1 * 17 + k], x2 = sXr[n2 * 17 + k];
                acc[0][0] = fmaf(x0, w.x, acc[0][0]); acc[0][1] = fmaf(x0, w.y, acc[0][1]);
                acc[0][2] = fmaf(x0, w.z, acc[0][2]); acc[0][3] = fmaf(x0, w.w, acc[0][3]);
                acc[1][0] = fmaf(x1, w.x, acc[1][0]); acc[1][1] = fmaf(x1, w.y, acc[1][1]);
                acc[1][2] = fmaf(x1, w.z, acc[1][2]); acc[1][3] = fmaf(x1, w.w, acc[1][3]);
                acc[2][0] = fmaf(x2, w.x, acc[2][0]); acc[2][1] = fmaf(x2, w.y, acc[2][1]);
                acc[2][2] = fmaf(x2, w.z, acc[2][2]); acc[2][3] = fmaf(x2, w.w, acc[2][3]);
            }
            float4 bias = *(const float4*)&sInb[c4];
            for (int j = 0; j < jcnt; j++) {
                int n = ng + 32 * j;
                f16x4 o;
                o.x = (f16)(acc[j][0] + bias.x);
                o.y = (f16)(acc[j][1] + bias.y);
                o.z = (f16)(acc[j][2] + bias.z);
                o.w = (f16)(acc[j][3] + bias.w);
                *(f16x4*)&sx[n * SXP + c4] = o;
            }
        }
    } else {
        #pragma unroll
        for (int g = 0; g < 2; g++) {
            const f16x8* pv8 = (const f16x8*)(prevPre + (size_t)(b2 + g) * (NN * CC));
            f16* sx = g ? sxB : sxA;
            for (int i8 = t; i8 < NN * CC / 8; i8 += TPB) {
                U16x8 v; v.v = pv8[i8];
                int n = i8 >> 3, c8 = (i8 & 7) << 3;
                U16x8 o;
                #pragma unroll
                for (int j = 0; j < 8; j++) {
                    float a = fmaf((float)v.e[j], sST[c8 + j], sST[CC + c8 + j]);
                    o.e[j] = (f16)(a > 0.0f ? a : 0.0f);
                }
                *(f16x8*)&sx[n * SXP + c8] = o.v;
            }
        }
    }
    __syncthreads();

    // ---------------- phase 3: h = x @ W via MFMA, both graphs; C f16 overlay
    {
        const int nt = wv & 3, m0 = wv >> 2;
        const f16x8 bf0 = *(const f16x8*)&sWt[(nt * 16 + lr) * SWP + lg * 8];
        const f16x8 bf1 = *(const f16x8*)&sWt[(nt * 16 + lr) * SWP + 32 + lg * 8];
        f16x8 aA0[3], aA1[3], aB0[3], aB1[3];
        #pragma unroll
        for (int mi = 0; mi < 3; mi++) {
            const int mt = m0 + 2 * mi;
            aA0[mi] = *(const f16x8*)&sxA[(mt * 16 + lr) * SXP + lg * 8];
            aA1[mi] = *(const f16x8*)&sxA[(mt * 16 + lr) * SXP + 32 + lg * 8];
            aB0[mi] = *(const f16x8*)&sxB[(mt * 16 + lr) * SXP + lg * 8];
            aB1[mi] = *(const f16x8*)&sxB[(mt * 16 + lr) * SXP + 32 + lg * 8];
        }
        __syncthreads();   // all sx/sWt reads done; sh writes may begin
        #pragma unroll
        for (int mi = 0; mi < 3; mi++) {
            const int mt = m0 + 2 * mi;
            const int row = mt * 16 + lg * 4, col = nt * 16 + lr;
            f32x4 accA = {0.0f, 0.0f, 0.0f, 0.0f};
            accA = __builtin_amdgcn_mfma_f32_16x16x32_f16(aA0[mi], bf0, accA, 0, 0, 0);
            accA = __builtin_amdgcn_mfma_f32_16x16x32_f16(aA1[mi], bf1, accA, 0, 0, 0);
            #pragma unroll
            for (int r = 0; r < 4; r++)
                sxA[(row + r) * SXP + col] = (f16)accA[r];
            f32x4 accB = {0.0f, 0.0f, 0.0f, 0.0f};
            accB = __builtin_amdgcn_mfma_f32_16x16x32_f16(aB0[mi], bf0, accB, 0, 0, 0);
            accB = __builtin_amdgcn_mfma_f32_16x16x32_f16(aB1[mi], bf1, accB, 0, 0, 0);
            #pragma unroll
            for (int r = 0; r < 4; r++)
                sxB[(row + r) * SXP + col] = (f16)accB[r];
        }
    }
    __syncthreads();

    // ---------------- phase 4: attention scores, 720 items (all threads)
    for (int i = t; i < 2 * NH * NN; i += TPB) {
        int g = i / (NH * NN), r = i - g * (NH * NN);
        int hh = r / NN, n = r - hh * NN;
        const f16* sh = g ? sxB : sxA;
        U16x8 h0, h1;
        h0.v = *(const f16x8*)&sh[n * SXP + hh * HD];
        h1.v = *(const f16x8*)&sh[n * SXP + hh * HD + 8];
        float a = 0.0f, d = 0.0f;
        #pragma unroll
        for (int j = 0; j < 8; j++) {
            a = fmaf((float)h0.e[j], sAs[hh * HD + j], a);
            a = fmaf((float)h1.e[j], sAs[hh * HD + 8 + j], a);
            d = fmaf((float)h0.e[j], sAd[hh * HD + j], d);
            d = fmaf((float)h1.e[j], sAd[hh * HD + 8 + j], d);
        }
        sSrc[i] = a; sDst[i] = d;
    }
    __syncthreads();

    // ---------------- phase 5: positional-slot softmax, 720 items
    for (int i = t; i < 2 * NH * NN; i += TPB) {
        int g = i / (NH * NN), r = i - g * (NH * NN);
        int hh = r / NN, n = r - hh * NN;
        int y = n / 9, x = n - y * 9;
        float si = sSrc[i];
        const float* dst = &sDst[(g * NH + hh) * NN];
        float e[NSLOT];
        #pragma unroll
        for (int xx = 0; xx < 9; xx++) {
            int dx = xx > x ? xx - x : x - xx;
            float ee = si + dst[y * 9 + xx];
            ee = ee > 0.0f ? ee : 0.2f * ee;
            e[xx] = (dx <= 4) ? ee : -1e30f;
        }
        #pragma unroll
        for (int yy = 0; yy < 10; yy++) {
            int dy = yy > y ? yy - y : y - yy;
            float ee = si + dst[yy * 9 + x];
            ee = ee > 0.0f ? ee : 0.2f * ee;
            e[9 + yy] = (dy >= 1 && dy <= 5) ? ee : -1e30f;
        }
        float m = e[0];
        #pragma unroll
        for (int k = 1; k < NSLOT; k++) m = fmaxf(m, e[k]);
        float p[NSLOT];
        float s = 0.0f;
        #pragma unroll
        for (int k = 0; k < NSLOT; k++) { p[k] = __expf(e[k] - m); s += p[k]; }
        float inv = 1.0f / s;
        f16* pr = &sPh[i * PPITCH];
        #pragma unroll
        for (int q = 0; q < 5; q++) {
            U16x4 o;
            #pragma unroll
            for (int j = 0; j < 4; j++) {
                int k = 4 * q + j;
                o.e[j] = (k < NSLOT) ? (f16)(p[k] * inv) : (f16)0;
            }
            *(f16x4*)&pr[4 * q] = o.v;
        }
    }
    __syncthreads();

    // ---------------- phase 6: out = attn @ h, both graphs
    const int hh2 = cq >> 2;
    float lsum[2][4] = {}, lsq[2][4] = {};
    #pragma unroll
    for (int g = 0; g < 2; g++) {
        const f16* sh = g ? sxB : sxA;
        const f16* phBase = &sPh[g * (NH * NN) * PPITCH];
        f16* op = outPre + (size_t)(b2 + g) * (NN * CC);
        for (int j = 0; j < jcnt; j++) {
            int n = ng + 32 * j;
            int y = n / 9, x = n - y * 9;
            const f16* pr = &phBase[(hh2 * NN + n) * PPITCH];
            U16x4 P0, P1, P2, P3, P4;
            P0.v = *(const f16x4*)&pr[0];
            P1.v = *(const f16x4*)&pr[4];
            P2.v = *(const f16x4*)&pr[8];
            P3.v = *(const f16x4*)&pr[12];
            P4.v = *(const f16x4*)&pr[16];
            float a0 = 0.0f, a1 = 0.0f, a2 = 0.0f, a3 = 0.0f;
            #pragma unroll
            for (int xx = 0; xx < 9; xx++) {
                float p = (xx < 4) ? (float)P0.e[xx]
                        : (xx < 8) ? (float)P1.e[xx - 4] : (float)P2.e[0];
                U16x4 h4; h4.v = *(const f16x4*)&sh[(y * 9 + xx) * SXP + c4];
                a0 = fmaf((float)h4.e[0], p, a0); a1 = fmaf((float)h4.e[1], p, a1);
                a2 = fmaf((float)h4.e[2], p, a2); a3 = fmaf((float)h4.e[3], p, a3);
            }
            #pragma unroll
            for (int yy = 0; yy < 10; yy++) {
                int k = 9 + yy;
                float p = (k < 12) ? (float)P2.e[k - 8]
                        : (k < 16) ? (float)P3.e[k - 12] : (float)P4.e[k - 16];
                U16x4 h4; h4.v = *(const f16x4*)&sh[(yy * 9 + x) * SXP + c4];
                a0 = fmaf((float)h4.e[0], p, a0); a1 = fmaf((float)h4.e[1], p, a1);
                a2 = fmaf((float)h4.e[2], p, a2); a3 = fmaf((float)h4.e[3], p, a3);
            }
            U16x4 o;
            o.e[0] = (f16)a0; o.e[1] = (f16)a1; o.e[2] = (f16)a2; o.e[3] = (f16)a3;
            *(f16x4*)&op[n * CC + c4] = o.v;
            float r0 = (float)o.e[0], r1 = (float)o.e[1];
            float r2 = (float)o.e[2], r3 = (float)o.e[3];
            lsum[g][0] += r0; lsum[g][1] += r1; lsum[g][2] += r2; lsum[g][3] += r3;
            lsq[g][0] = fmaf(r0, r0, lsq[g][0]); lsq[g][1] = fmaf(r1, r1, lsq[g][1]);
            lsq[g][2] = fmaf(r2, r2, lsq[g][2]); lsq[g][3] = fmaf(r3, r3, lsq[g][3]);
        }
    }
    __syncthreads();   // sPh dead beyond here

    // ---------------- phase 7: BN partials (shfl within wave, then 8-wave)
    #pragma unroll
    for (int g = 0; g < 2; g++) {
        #pragma unroll
        for (int q = 0; q < 4; q++) {
            float v = lsum[g][q];
            v += __shfl_xor(v, 16); v += __shfl_xor(v, 32);
            lsum[g][q] = v;
            float w2 = lsq[g][q];
            w2 += __shfl_xor(w2, 16); w2 += __shfl_xor(w2, 32);
            lsq[g][q] = w2;
        }
    }
    if (lg == 0) {
        #pragma unroll
        for (int g = 0; g < 2; g++) {
            float4 a; a.x = lsum[g][0]; a.y = lsum[g][1]; a.z = lsum[g][2]; a.w = lsum[g][3];
            float4 c; c.x = lsq[g][0];  c.y = lsq[g][1];  c.z = lsq[g][2];  c.w = lsq[g][3];
            *(float4*)&sRa[(g * 8 + wv) * CC + lr * 4] = a;
            *(float4*)&sRb[(g * 8 + wv) * CC + lr * 4] = c;
        }
    }
    __syncthreads();
    if (t < 2 * CC) {
        int g = t >> 6, c = t & 63;
        float s = 0.0f, q2 = 0.0f;
        #pragma unroll
        for (int w = 0; w < 8; w++) {
            s  += sRa[(g * 8 + w) * CC + c];
            q2 += sRb[(g * 8 + w) * CC + c];
        }
        partial[(size_t)(b2 + g) * CC + c] = s;
        partialSq[(size_t)(b2 + g) * CC + c] = q2;
    }
}

// ------------------------------------------------------------- BN statistics
__global__ __launch_bounds__(256) void k_stats(
    const float* __restrict__ partial, const float* __restrict__ partialSq,
    const float* __restrict__ gamma, const float* __restrict__ beta,
    float* __restrict__ st)
{
    const int c = blockIdx.x, t = threadIdx.x;
    float s = 0.0f, q = 0.0f;
    for (int b = t; b < BB; b += 256) {
        s += partial[(size_t)b * CC + c];
        q += partialSq[(size_t)b * CC + c];
    }
    __shared__ float rs[256], rq[256];
    rs[t] = s; rq[t] = q;
    __syncthreads();
    for (int o = 128; o > 0; o >>= 1) {
        if (t < o) { rs[t] += rs[t + o]; rq[t] += rq[t + o]; }
        __syncthreads();
    }
    if (t == 0) {
        const float cntInv = 1.0f / (float)(BB * NN);
        float mean = rs[0] * cntInv;
        float var  = rq[0] * cntInv - mean * mean;
        float sc = gamma[c] * rsqrtf(var + 1e-5f);
        st[c] = sc;
        st[CC + c] = beta[c] - mean * sc;
    }
}

// ------------------------------------------------------------------- final
__global__ __launch_bounds__(256) void k_final(
    const f16* __restrict__ pre, const float* __restrict__ st,
    const float* __restrict__ outW, const float* __restrict__ outb,
    float* __restrict__ out)
{
    __shared__ float sM[CC];
    __shared__ float sPart[4][CC];
    const int b = blockIdx.x, t = threadIdx.x;
    const int c = t & 63, p = t >> 6;
    const f16* pv = pre + (size_t)b * (NN * CC);
    float s = st[c], sft = st[CC + c];
    float a = 0.0f;
    int nBeg = p * 23, nEnd = nBeg + 23 < NN ? nBeg + 23 : NN;
    for (int n = nBeg; n < nEnd; n++) {
        float v = fmaf((float)pv[n * CC + c], s, sft);
        a += (v > 0.0f ? v : 0.0f);
    }
    sPart[p][c] = a;
    __syncthreads();
    if (t < CC)
        sM[t] = (sPart[0][t] + sPart[1][t] + sPart[2][t] + sPart[3][t]) * (1.0f / (float)NN);
    __syncthreads();
    if (t < DOUT) {
        float acc = outb[t];
        #pragma unroll
        for (int cc2 = 0; cc2 < CC; cc2++) acc = fmaf(sM[cc2], outW[cc2 * DOUT + t], acc);
        out[(size_t)b * DOUT + t] = acc;
    }
}

// ------------------------------------------------------------------ launch
extern "C" void kernel_launch(void* const* d_in, const int* in_sizes, int n_in,
                              void* d_out, int out_size, void* d_ws, size_t ws_size,
                              hipStream_t stream) {
    (void)in_sizes; (void)n_in; (void)out_size; (void)ws_size;

    const float* bp   = (const float*)d_in[0];
    const float* inW  = (const float*)d_in[1];
    const float* inb  = (const float*)d_in[2];
    const float* W0   = (const float*)d_in[3];
    const float* as0  = (const float*)d_in[4];
    const float* ad0  = (const float*)d_in[5];
    const float* g0   = (const float*)d_in[6];
    const float* b0   = (const float*)d_in[7];
    const float* W1   = (const float*)d_in[8];
    const float* as1  = (const float*)d_in[9];
    const float* ad1  = (const float*)d_in[10];
    const float* b1g  = (const float*)d_in[11];
    const float* b1   = (const float*)d_in[12];
    const float* outW = (const float*)d_in[13];
    const float* outb = (const float*)d_in[14];
    float* out = (float*)d_out;

    unsigned char* ws = (unsigned char*)d_ws;
    f16*   outPre    = (f16*)ws;                           // 23,592,960 B
    float* partial   = (float*)(ws + 23592960);            // 524,288 B
    float* partialSq = (float*)(ws + 23592960 + 524288);   // 524,288 B
    float* st0       = (float*)(ws + 23592960 + 1048576);
    float* st1       = st0 + 2 * CC;

    k_gat<0><<<GRID, TPB, 0, stream>>>(bp, inW, inb, nullptr, nullptr,
                                       W0, as0, ad0, outPre, partial, partialSq);
    k_stats<<<CC, 256, 0, stream>>>(partial, partialSq, g0, b0, st0);
    k_gat<1><<<GRID, TPB, 0, stream>>>(nullptr, nullptr, nullptr, outPre, st0,
                                       W1, as1, ad1, outPre, partial, partialSq);
    k_stats<<<CC, 256, 0, stream>>>(partial, partialSq, b1g, b1, st1);
    k_final<<<BB, 256, 0, stream>>>(outPre, st1, outW, outb, out);
}